// Round 7
// baseline (68.915 us; speedup 1.0000x reference)
//
#include <hip/hip_runtime.h>

// ShiftMap fused, v7:
//  - kernel 1: x-interpolate 16x16 control grid to Xsc[b][16][1024] (float2,
//    pre-scaled) in d_ws.
//  - kernel 2: per block (= one row): cooperative y-interp of 4 xsc rows into
//    an LDS shift-row (latency paid once, coalesced). Per pixel: LDS read ->
//    coords -> interior fast path with NO clamps/masks (offsets base+i*W);
//    rare border path folds zeros-padding into weights. All gathers
//    unconditional float4 row-loads.
//  - XCD-aware swizzle keeps each batch's 4MB image in one XCD's L2.

static constexpr float A = -0.75f;  // PyTorch bicubic coefficient
static constexpr int NXCD = 8;

typedef float f4u __attribute__((ext_vector_type(4), aligned(4)));

__device__ __forceinline__ void cubic_weights(float t, float* w) {
    float t2 = t * t;
    float s  = 1.0f - t;
    w[1] = (A + 2.0f) * t * t2 - (A + 3.0f) * t2 + 1.0f;       // dist = t
    w[2] = (A + 2.0f) * s * s * s - (A + 3.0f) * s * s + 1.0f; // dist = 1-t
    float u = 1.0f + t;
    w[0] = A * (u * (u * (u - 5.0f) + 8.0f) - 4.0f);           // dist = 1+t
    float v = 2.0f - t;
    w[3] = A * (v * (v * (v - 5.0f) + 8.0f) - 4.0f);           // dist = 2-t
}

// ---- kernel 1: Xsc[b][cy][x] = (smy(x)*half_h, smx(x)*half_w) ----
__global__ __launch_bounds__(256) void xinterp_kernel(
    const float* __restrict__ smap,  // (B,CH,CW,2)
    float2* __restrict__ xsc,        // (B,CH,W)
    int W, int CH, int CW, float scale_x, float half_h, float half_w)
{
    const int x  = blockIdx.x * 256 + threadIdx.x;
    const int cy = blockIdx.y;
    const int b  = blockIdx.z;
    if (x >= W) return;

    const float sx  = x * scale_x;
    const float fx0 = floorf(sx);
    const int   cx0 = (int)fx0;
    float wx[4];
    cubic_weights(sx - fx0, wx);

    const float* row = smap + (((size_t)b * CH + cy) * CW) * 2;
    float vy = 0.0f, vx = 0.0f;
    #pragma unroll
    for (int j = 0; j < 4; ++j) {
        const int cx = min(max(cx0 - 1 + j, 0), CW - 1);
        vy += wx[j] * row[cx * 2 + 0];
        vx += wx[j] * row[cx * 2 + 1];
    }
    xsc[((size_t)b * CH + cy) * W + x] = make_float2(vy * half_h, vx * half_w);
}

// ---- kernel 2: warp ----
template <int PX>
__global__ __launch_bounds__(256, 4) void shiftmap_warp_kernel(
    const float* __restrict__ img,    // (B,1,H,W)
    const float2* __restrict__ xsc,   // (B,CH,W)
    float* __restrict__ out,          // (B,1,H,W)
    int H, int W, int CH, int nblocks, float scale_y)
{
    // XCD-aware swizzle: dispatch d lands on XCD d%8 -> contiguous work band.
    const int d    = blockIdx.x;
    const int per  = nblocks / NXCD;
    const int work = (d % NXCD) * per + d / NXCD;
    const int y = work % H;
    const int b = work / H;
    const int tid = threadIdx.x;

    __shared__ float2 s_sm[1024];   // this row's shift field (8 KB)

    // row-uniform y-interp weights + clamped control-row base pointers
    const float sy  = y * scale_y;
    const float fy0 = floorf(sy);
    const int   cy0 = (int)fy0;
    float wy[4];
    cubic_weights(sy - fy0, wy);
    const float2* xb_ = xsc + (size_t)b * CH * W;
    const float2* bp0 = xb_ + (size_t)min(max(cy0 - 1, 0), CH - 1) * W;
    const float2* bp1 = xb_ + (size_t)min(max(cy0    , 0), CH - 1) * W;
    const float2* bp2 = xb_ + (size_t)min(max(cy0 + 1, 0), CH - 1) * W;
    const float2* bp3 = xb_ + (size_t)min(max(cy0 + 2, 0), CH - 1) * W;

    // cooperative y-interp: 16 coalesced loads + 8 FMA per px, once per row
    #pragma unroll
    for (int k = 0; k < PX; ++k) {
        const int x = tid + k * 256;
        const float2 c0 = bp0[x], c1 = bp1[x], c2 = bp2[x], c3 = bp3[x];
        float2 r;
        r.x = wy[0] * c0.x + wy[1] * c1.x + wy[2] * c2.x + wy[3] * c3.x;
        r.y = wy[0] * c0.y + wy[1] * c1.y + wy[2] * c2.y + wy[3] * c3.y;
        s_sm[x] = r;
    }
    __syncthreads();

    const float* imgb = img + (size_t)b * H * W;
    float* outb = out + (size_t)b * H * W + (size_t)y * W;

    // ---- per-pixel: coords + weights + offsets (interior = no clamps/masks) ----
    int   off[PX][4];
    float wxm[PX][4], wym[PX][4];
    #pragma unroll
    for (int k = 0; k < PX; ++k) {
        const int x = tid + k * 256;
        const float2 sm = s_sm[x];
        const float ix = (float)x + sm.y;
        const float iy = (float)y + sm.x;
        const float ixf = floorf(ix), iyf = floorf(iy);
        const int ix0 = (int)ixf, iy0 = (int)iyf;
        float gwx[4], gwy[4];
        cubic_weights(ix - ixf, gwx);
        cubic_weights(iy - iyf, gwy);

        if (__builtin_expect((ix0 >= 1) & (ix0 <= W - 3) &
                             (iy0 >= 1) & (iy0 <= H - 3), 1)) {
            const int base = (iy0 - 1) * W + (ix0 - 1);
            off[k][0] = base;         off[k][1] = base + W;
            off[k][2] = base + 2 * W; off[k][3] = base + 3 * W;
            wxm[k][0] = gwx[0]; wxm[k][1] = gwx[1];
            wxm[k][2] = gwx[2]; wxm[k][3] = gwx[3];
            wym[k][0] = gwy[0]; wym[k][1] = gwy[1];
            wym[k][2] = gwy[2]; wym[k][3] = gwy[3];
        } else {
            // border: clamp addresses, fold zeros-padding into weights
            const int xb = min(max(ix0 - 1, 0), W - 4);
            const int delta = xb - (ix0 - 1);
            float n0 = 0.f, n1 = 0.f, n2 = 0.f, n3 = 0.f;
            if      (delta ==  0) { n0 = gwx[0]; n1 = gwx[1]; n2 = gwx[2]; n3 = gwx[3]; }
            else if (delta ==  1) { n0 = gwx[1]; n1 = gwx[2]; n2 = gwx[3]; }
            else if (delta ==  2) { n0 = gwx[2]; n1 = gwx[3]; }
            else if (delta ==  3) { n0 = gwx[3]; }
            else if (delta == -1) { n1 = gwx[0]; n2 = gwx[1]; n3 = gwx[2]; }
            else if (delta == -2) { n2 = gwx[0]; n3 = gwx[1]; }
            else if (delta == -3) { n3 = gwx[0]; }
            wxm[k][0] = n0; wxm[k][1] = n1; wxm[k][2] = n2; wxm[k][3] = n3;
            #pragma unroll
            for (int i = 0; i < 4; ++i) {
                const int yy = iy0 - 1 + i;
                const bool ok = (yy >= 0) & (yy < H);
                const int yc = min(max(yy, 0), H - 1);
                wym[k][i] = ok ? gwy[i] : 0.0f;
                off[k][i] = yc * W + xb;
            }
        }
    }

    // ---- gathers: all unconditional float4 row-loads ----
    f4u f[PX][4];
    #pragma unroll
    for (int k = 0; k < PX; ++k) {
        #pragma unroll
        for (int i = 0; i < 4; ++i)
            f[k][i] = *reinterpret_cast<const f4u*>(imgb + off[k][i]);
    }

    // ---- FMA + store ----
    #pragma unroll
    for (int k = 0; k < PX; ++k) {
        const int x = tid + k * 256;
        float acc = 0.0f;
        #pragma unroll
        for (int i = 0; i < 4; ++i) {
            acc += wym[k][i] * (wxm[k][0] * f[k][i].x + wxm[k][1] * f[k][i].y
                              + wxm[k][2] * f[k][i].z + wxm[k][3] * f[k][i].w);
        }
        outb[x] = acc;
    }
}

// ---- fallback (v3 single-kernel) if ws_size is too small ----
template <int PX_PER_THREAD>
__global__ __launch_bounds__(256) void shiftmap_warp_fallback(
    const float* __restrict__ img, const float* __restrict__ smap,
    float* __restrict__ out, int H, int W, int CH, int CW, int nblocks)
{
    const int d   = blockIdx.x;
    const int per = nblocks / NXCD;
    const int work = (d % NXCD) * per + d / NXCD;
    const int y = work % H;
    const int b = work / H;
    const int tid = threadIdx.x;

    __shared__ float s_row[64];
    const float scale_y = (float)((double)(CH - 1) / (double)(H - 1));
    const float scale_x = (float)((double)(CW - 1) / (double)(W - 1));

    if (tid < CW * 2) {
        const int c = tid >> 1, ch = tid & 1;
        const float sy = y * scale_y;
        const float fy0 = floorf(sy);
        const int cy0 = (int)fy0;
        float wy[4];
        cubic_weights(sy - fy0, wy);
        float v = 0.0f;
        #pragma unroll
        for (int i = 0; i < 4; ++i) {
            const int cy = min(max(cy0 - 1 + i, 0), CH - 1);
            v += wy[i] * smap[(((size_t)b * CH + cy) * CW + c) * 2 + ch];
        }
        s_row[tid] = v;
    }
    __syncthreads();

    const float half_w = 0.5f * (float)(W - 1);
    const float half_h = 0.5f * (float)(H - 1);
    const float* imgb = img + (size_t)b * H * W;
    float* outb = out + (size_t)b * H * W + (size_t)y * W;

    #pragma unroll
    for (int k = 0; k < PX_PER_THREAD; ++k) {
        const int x = tid + k * 256;
        const float sx = x * scale_x;
        const float fx0 = floorf(sx);
        const int cx0 = (int)fx0;
        float wx[4];
        cubic_weights(sx - fx0, wx);
        float smy = 0.0f, smx = 0.0f;
        #pragma unroll
        for (int j = 0; j < 4; ++j) {
            const int cx = min(max(cx0 - 1 + j, 0), CW - 1);
            smy += wx[j] * s_row[cx * 2 + 0];
            smx += wx[j] * s_row[cx * 2 + 1];
        }
        const float ix = (float)x + smx * half_w;
        const float iy = (float)y + smy * half_h;
        const float ixf = floorf(ix), iyf = floorf(iy);
        const int ix0 = (int)ixf, iy0 = (int)iyf;
        float gwx[4], gwy[4];
        cubic_weights(ix - ixf, gwx);
        cubic_weights(iy - iyf, gwy);
        float acc = 0.0f;
        #pragma unroll
        for (int i = 0; i < 4; ++i) {
            const int yy = iy0 - 1 + i;
            const bool vy = (yy >= 0) && (yy < H);
            const int yc = min(max(yy, 0), H - 1);
            const float* row = imgb + (size_t)yc * W;
            float r = 0.0f;
            #pragma unroll
            for (int j = 0; j < 4; ++j) {
                const int xx = ix0 - 1 + j;
                const bool v = vy && (xx >= 0) && (xx < W);
                const int xc = min(max(xx, 0), W - 1);
                r += gwx[j] * (v ? row[xc] : 0.0f);
            }
            acc += gwy[i] * r;
        }
        outb[x] = acc;
    }
}

extern "C" void kernel_launch(void* const* d_in, const int* in_sizes, int n_in,
                              void* d_out, int out_size, void* d_ws, size_t ws_size,
                              hipStream_t stream) {
    const float* img  = (const float*)d_in[0];  // (B,1,1024,1024) fp32
    const float* smap = (const float*)d_in[1];  // (B,16,16,2) fp32
    float* out = (float*)d_out;

    const int H = 1024, W = 1024;
    const int CH = 16, CW = 16;
    const int B = in_sizes[0] / (H * W);
    const int nblocks = H * B;

    const float scale_y = (float)((double)(CH - 1) / (double)(H - 1));
    const float scale_x = (float)((double)(CW - 1) / (double)(W - 1));
    const float half_h = 0.5f * (float)(H - 1);
    const float half_w = 0.5f * (float)(W - 1);

    const size_t ws_needed = (size_t)B * CH * W * sizeof(float2);
    if (ws_size >= ws_needed) {
        float2* xsc = (float2*)d_ws;
        dim3 g1(W / 256, CH, B);
        xinterp_kernel<<<g1, 256, 0, stream>>>(smap, xsc, W, CH, CW,
                                               scale_x, half_h, half_w);
        dim3 g2(nblocks);
        shiftmap_warp_kernel<4><<<g2, 256, 0, stream>>>(img, xsc, out,
                                                        H, W, CH, nblocks, scale_y);
    } else {
        dim3 g2(nblocks);
        shiftmap_warp_fallback<4><<<g2, 256, 0, stream>>>(img, smap, out,
                                                          H, W, CH, CW, nblocks);
    }
}

// Round 8
// 48.262 us; speedup vs baseline: 1.4279x; 1.4279x over previous
//
#include <hip/hip_runtime.h>

// ShiftMap fused, v8 = v3 structure (the 48us winner) + targeted trims:
//  - single kernel, one block per (row,batch), tiny LDS control row, no phases
//  - interior gather as 4 unaligned dwordx4 row-loads (was 16 scalar loads)
//  - control row padded to cx in [-1,17] at stage time -> no per-px clamps
//  - Keys partition-of-unity: w3 = 1 - w0 - w1 - w2
//  - XCD-aware swizzle keeps each batch's 4MB image in one XCD's L2.

static constexpr float A = -0.75f;  // PyTorch bicubic coefficient
static constexpr int NXCD = 8;

typedef float f4u __attribute__((ext_vector_type(4), aligned(4)));

__device__ __forceinline__ void cubic_weights(float t, float* w) {
    float t2 = t * t;
    float s  = 1.0f - t;
    w[1] = (A + 2.0f) * t * t2 - (A + 3.0f) * t2 + 1.0f;       // dist = t
    w[2] = (A + 2.0f) * s * s * s - (A + 3.0f) * s * s + 1.0f; // dist = 1-t
    float u = 1.0f + t;
    w[0] = A * (u * (u * (u - 5.0f) + 8.0f) - 4.0f);           // dist = 1+t
    w[3] = 1.0f - w[0] - w[1] - w[2];                          // partition of unity
}

template <int PX>
__global__ __launch_bounds__(256) void shiftmap_warp_kernel(
    const float* __restrict__ img,   // (B,1,H,W)
    const float* __restrict__ smap,  // (B,CH,CW,2)
    float* __restrict__ out,         // (B,1,H,W)
    int H, int W, int CH, int CW, int nblocks)
{
    // XCD-aware swizzle: dispatch d lands on XCD d%8 -> contiguous work band.
    const int d   = blockIdx.x;
    const int per = nblocks / NXCD;
    const int work = (d % NXCD) * per + d / NXCD;
    const int y = work % H;                    // image row
    const int b = work / H;                    // batch
    const int tid = threadIdx.x;

    // padded, y-interpolated control row: cx in [-1..17], 2 channels (38 floats)
    __shared__ float s_row[40];

    const float scale_y = (float)((double)(CH - 1) / (double)(H - 1));
    const float scale_x = (float)((double)(CW - 1) / (double)(W - 1));

    if (tid < 38) {
        const int c  = (tid >> 1) - 1;                 // -1..17
        const int cc = min(max(c, 0), CW - 1);         // clamp once at stage
        const int ch = tid & 1;
        const float sy  = y * scale_y;
        const float fy0 = floorf(sy);
        const int   cy0 = (int)fy0;
        float wy[4];
        cubic_weights(sy - fy0, wy);
        float v = 0.0f;
        #pragma unroll
        for (int i = 0; i < 4; ++i) {
            const int cy = min(max(cy0 - 1 + i, 0), CH - 1);
            v += wy[i] * smap[(((size_t)b * CH + cy) * CW + cc) * 2 + ch];
        }
        s_row[tid] = v;
    }
    __syncthreads();

    const float half_w = 0.5f * (float)(W - 1);
    const float half_h = 0.5f * (float)(H - 1);
    const float* imgb = img + (size_t)b * H * W;
    float* outb = out + (size_t)b * H * W + (size_t)y * W;

    #pragma unroll
    for (int k = 0; k < PX; ++k) {
        const int x = tid + k * 256;

        // ---- x-interp of padded control row (no clamps) ----
        const float sx  = x * scale_x;
        const float fx0 = floorf(sx);
        const int   cx0 = (int)fx0;                    // 0..15
        float wx[4];
        cubic_weights(sx - fx0, wx);
        const float* sr = s_row + cx0 * 2;             // taps at sr[0..7]
        const float smy = wx[0] * sr[0] + wx[1] * sr[2] + wx[2] * sr[4] + wx[3] * sr[6];
        const float smx = wx[0] * sr[1] + wx[1] * sr[3] + wx[2] * sr[5] + wx[3] * sr[7];

        // ---- sampling coords (mesh folded analytically) ----
        const float ix = (float)x + smx * half_w;
        const float iy = (float)y + smy * half_h;
        const float ixf = floorf(ix), iyf = floorf(iy);
        const int ix0 = (int)ixf, iy0 = (int)iyf;
        float gwx[4], gwy[4];
        cubic_weights(ix - ixf, gwx);
        cubic_weights(iy - iyf, gwy);

        // ---- 4x4 bicubic gather ----
        float acc = 0.0f;
        if (__builtin_expect((ix0 >= 1) & (ix0 <= W - 3) &
                             (iy0 >= 1) & (iy0 <= H - 3), 1)) {
            // interior fast path: 4 unaligned float4 row-loads
            const float* p = imgb + (size_t)(iy0 - 1) * W + (ix0 - 1);
            const f4u r0 = *reinterpret_cast<const f4u*>(p);
            const f4u r1 = *reinterpret_cast<const f4u*>(p + W);
            const f4u r2 = *reinterpret_cast<const f4u*>(p + 2 * W);
            const f4u r3 = *reinterpret_cast<const f4u*>(p + 3 * W);
            acc  = gwy[0] * (gwx[0] * r0.x + gwx[1] * r0.y + gwx[2] * r0.z + gwx[3] * r0.w);
            acc += gwy[1] * (gwx[0] * r1.x + gwx[1] * r1.y + gwx[2] * r1.z + gwx[3] * r1.w);
            acc += gwy[2] * (gwx[0] * r2.x + gwx[1] * r2.y + gwx[2] * r2.z + gwx[3] * r2.w);
            acc += gwy[3] * (gwx[0] * r3.x + gwx[1] * r3.y + gwx[2] * r3.z + gwx[3] * r3.w);
        } else {
            // border: zeros padding with per-tap masks (rare)
            #pragma unroll
            for (int i = 0; i < 4; ++i) {
                const int yy = iy0 - 1 + i;
                const bool vy = (yy >= 0) && (yy < H);
                const int yc = min(max(yy, 0), H - 1);
                const float* row = imgb + (size_t)yc * W;
                float r = 0.0f;
                #pragma unroll
                for (int j = 0; j < 4; ++j) {
                    const int xx = ix0 - 1 + j;
                    const bool v = vy && (xx >= 0) && (xx < W);
                    const int xc = min(max(xx, 0), W - 1);
                    r += gwx[j] * (v ? row[xc] : 0.0f);
                }
                acc += gwy[i] * r;
            }
        }
        outb[x] = acc;
    }
}

extern "C" void kernel_launch(void* const* d_in, const int* in_sizes, int n_in,
                              void* d_out, int out_size, void* d_ws, size_t ws_size,
                              hipStream_t stream) {
    const float* img  = (const float*)d_in[0];  // (B,1,1024,1024) fp32
    const float* smap = (const float*)d_in[1];  // (B,16,16,2) fp32
    float* out = (float*)d_out;

    const int H = 1024, W = 1024;
    const int CH = 16, CW = 16;
    const int B = in_sizes[0] / (H * W);
    const int nblocks = H * B;   // one block per (row, batch); 8192 (mult of 8)

    dim3 block(256);
    dim3 grid(nblocks);
    shiftmap_warp_kernel<4><<<grid, block, 0, stream>>>(img, smap, out,
                                                        H, W, CH, CW, nblocks);
}